// Round 6
// baseline (208.942 us; speedup 1.0000x reference)
//
#include <hip/hip_runtime.h>
#include <hip/hip_bf16.h>

#define DD 256
#define NN 512

typedef __attribute__((ext_vector_type(8))) short short8;
typedef __attribute__((ext_vector_type(4))) float floatx4;

// ---- f32 -> bf16 round-to-nearest-even ----
__device__ __forceinline__ unsigned short f2bf(float f) {
  unsigned u = __float_as_uint(f);
  u += 0x7FFFu + ((u >> 16) & 1u);
  return (unsigned short)(u >> 16);
}
__device__ __forceinline__ unsigned pack2(float a, float b) {
  return (unsigned)f2bf(a) | ((unsigned)f2bf(b) << 16);
}

// ---- MFMA fragment loader (global bf16 rows, k contiguous) ----
__device__ __forceinline__ short8 ldfrag(const unsigned short* __restrict__ base,
                                         int row, int ld, int k, int lane) {
  return *(const short8*)(base + (row + (lane & 15)) * ld + k + ((lane >> 4) << 3));
}

template <int NF>
__device__ __forceinline__ void acc_zero(floatx4 acc[NF]) {
#pragma unroll
  for (int i = 0; i < NF; ++i) {
    acc[i][0] = 0.f; acc[i][1] = 0.f; acc[i][2] = 0.f; acc[i][3] = 0.f;
  }
}

// One wave accumulates C[16 x 16*NF] over compile-time K (full unroll -> MLP).
template <int NF, int K>
__device__ __forceinline__ void gemm_acc(floatx4 acc[NF],
    const unsigned short* __restrict__ A, int lda, int a_k0,
    const unsigned short* __restrict__ BT, int ldb, int b_k0,
    int m0, int n0, int lane) {
#pragma unroll
  for (int k = 0; k < K; k += 32) {
    short8 a = ldfrag(A, m0, lda, a_k0 + k, lane);
#pragma unroll
    for (int nf = 0; nf < NF; ++nf) {
      short8 b = ldfrag(BT, n0 + nf * 16, ldb, b_k0 + k, lane);
      acc[nf] = __builtin_amdgcn_mfma_f32_16x16x32_bf16(a, b, acc[nf], 0, 0, 0);
    }
  }
}

// Split-K combine across 4 waves via LDS; wave 0 ends with the full sum.
template <int NF>
__device__ __forceinline__ void ksplit_combine(floatx4 acc[NF], float* red,
                                               int wave, int lane) {
  const int W = 16 * NF;
  const int col = lane & 15;
  const int q = lane >> 4;
  if (wave > 0) {
    float* base = red + (wave - 1) * 16 * W;
#pragma unroll
    for (int nf = 0; nf < NF; ++nf)
#pragma unroll
      for (int r = 0; r < 4; ++r)
        base[(q * 4 + r) * W + nf * 16 + col] = acc[nf][r];
  }
  __syncthreads();
  if (wave == 0) {
#pragma unroll
    for (int nf = 0; nf < NF; ++nf)
#pragma unroll
      for (int r = 0; r < 4; ++r) {
        const int idx = (q * 4 + r) * W + nf * 16 + col;
        acc[nf][r] += red[idx] + red[16 * W + idx] + red[32 * W + idx];
      }
  }
}

// Epilogue for C-layout (col = lane&15, row = (lane>>4)*4 + r).
template <int NF, bool COLBIAS, bool ROWBIAS, bool RELU, bool OUTBF>
__device__ __forceinline__ void gemm_epi(floatx4 acc[NF],
    const float* __restrict__ bias, void* __restrict__ C, int ldc,
    int m0, int n0, int lane) {
  const int col = lane & 15;
  const int q = lane >> 4;
#pragma unroll
  for (int nf = 0; nf < NF; ++nf) {
    const int n = n0 + nf * 16 + col;
    const float cb = COLBIAS ? bias[n] : 0.0f;
#pragma unroll
    for (int r = 0; r < 4; ++r) {
      const int m = m0 + q * 4 + r;
      float v = acc[nf][r] + cb + (ROWBIAS ? bias[m] : 0.0f);
      if (RELU) v = fmaxf(v, 0.0f);
      if (OUTBF) ((unsigned short*)C)[m * ldc + n] = f2bf(v);
      else       ((float*)C)[m * ldc + n] = v;
    }
  }
}

// ---- device-scope grid barrier (all blocks co-resident: grid<=256, 33KB LDS)
__device__ __forceinline__ void gridbar(unsigned* cnt, unsigned* gen, unsigned nb) {
  __syncthreads();
  if (threadIdx.x == 0) {
    __threadfence();  // release this block's phase writes (L2 wb)
    const unsigned g = __hip_atomic_load(gen, __ATOMIC_RELAXED, __HIP_MEMORY_SCOPE_AGENT);
    const unsigned a = __hip_atomic_fetch_add(cnt, 1u, __ATOMIC_RELAXED, __HIP_MEMORY_SCOPE_AGENT);
    if (a == nb - 1u) {
      __threadfence();  // acquire all other blocks' writes
      __hip_atomic_store(cnt, 0u, __ATOMIC_RELAXED, __HIP_MEMORY_SCOPE_AGENT);
      __threadfence();  // release cnt reset before gen bump
      __hip_atomic_fetch_add(gen, 1u, __ATOMIC_RELAXED, __HIP_MEMORY_SCOPE_AGENT);
    } else {
      while (__hip_atomic_load(gen, __ATOMIC_RELAXED, __HIP_MEMORY_SCOPE_AGENT) == g)
        __builtin_amdgcn_s_sleep(2);
      __threadfence();  // acquire everything published before gen bump
    }
  }
  __syncthreads();
}

// ---------------------------------------------------------------------------
// prep: blocks 0..639 flat cvt (w1 128 | wa 256 | wb 128 | src 128)
//       blocks 640..895 transpose+cvt x,src -> xT,srcT [n][d]
//       block 0 also zeroes the grid-barrier state (ws is poisoned each run).
// ---------------------------------------------------------------------------
__global__ __launch_bounds__(256) void prep_kernel(
    const float* __restrict__ x, const float* __restrict__ src,
    const float* __restrict__ w1, const float* __restrict__ wa,
    const float* __restrict__ wb,
    unsigned short* __restrict__ w1b, unsigned short* __restrict__ wab,
    unsigned short* __restrict__ wbb, unsigned short* __restrict__ srcb,
    unsigned short* __restrict__ xT, unsigned short* __restrict__ srcT,
    unsigned* __restrict__ bar) {
  const int bid = blockIdx.x;
  const int tid = threadIdx.x;
  if (bid == 0 && tid < 8) bar[tid] = 0u;
  if (bid < 640) {
    const float* in; unsigned short* out; int off;
    if (bid < 128)      { in = w1;  out = w1b; off = bid; }
    else if (bid < 384) { in = wa;  out = wab; off = bid - 128; }
    else if (bid < 512) { in = wb;  out = wbb; off = bid - 384; }
    else                { in = src; out = srcb; off = bid - 512; }
    const int i = off * 1024 + tid * 4;
    const float4 v = *(const float4*)(in + i);
    *(uint2*)(out + i) = make_uint2(pack2(v.x, v.y), pack2(v.z, v.w));
  } else {
    __shared__ float tile[32][33];
    const int b = bid - 640;
    const float* in = (b >> 7) ? src : x;
    unsigned short* out = (b >> 7) ? srcT : xT;
    const int t = b & 127;
    const int n0 = (t >> 3) * 32;
    const int d0 = (t & 7) * 32;
    const int tx = tid & 31, ty = tid >> 5;
#pragma unroll
    for (int i = ty; i < 32; i += 8)
      tile[i][tx] = in[(d0 + i) * NN + n0 + tx];
    __syncthreads();
#pragma unroll
    for (int i = ty; i < 32; i += 8)
      out[(n0 + i) * DD + d0 + tx] = f2bf(tile[tx][i]);
  }
}

// ---------------------------------------------------------------------------
// Mega-kernel: 256 blocks x 256 threads; 5 phases; 4 grid barriers.
// ---------------------------------------------------------------------------
__global__ __launch_bounds__(256) void mega_kernel(
    const unsigned short* __restrict__ w1b, const unsigned short* __restrict__ xT,
    const unsigned short* __restrict__ srcT, const unsigned short* __restrict__ srcb,
    const unsigned short* __restrict__ wab, const unsigned short* __restrict__ wbb,
    const float* __restrict__ b1, const float* __restrict__ w2,
    const float* __restrict__ b2, const float* __restrict__ ba,
    const float* __restrict__ bb,
    float* __restrict__ aq, float* __restrict__ ak,
    unsigned short* __restrict__ msgTb, unsigned short* __restrict__ h2Tb,
    float* __restrict__ sc, float* __restrict__ y,
    unsigned* __restrict__ bar) {
  __shared__ __align__(16) char smem[33792];
  const int bid = blockIdx.x;
  const int tid = threadIdx.x;
  const int lane = tid & 63;
  const int wave = tid >> 6;
  unsigned* cnt = bar;
  unsigned* gen = bar + 4;

  // ===== Phase 1: aq[d][n] = w1q @ x (+b1), ak[d][n] = w1k @ src ===========
  {
    float* red = (float*)smem;  // 2 pairs x 16x32 = 4 KB
    const int job = bid * 4 + wave;       // 0..1023
    const int z = job >> 9;               // 0 -> aq, 1 -> ak
    const int ks = job & 1;               // K half
    const int tile = (job >> 1) & 255;
    const int m0 = (tile >> 4) * 16;      // d
    const int n0 = (tile & 15) * 32;      // token
    const unsigned short* BT = z ? srcT : xT;

    floatx4 acc[2]; acc_zero<2>(acc);
    gemm_acc<2, 128>(acc, w1b, NN, z * 256 + ks * 128, BT, DD, ks * 128, m0, n0, lane);

    const int col = lane & 15, q = lane >> 4;
    float* base = red + (wave >> 1) * 512;
    if (wave & 1) {
#pragma unroll
      for (int nf = 0; nf < 2; ++nf)
#pragma unroll
        for (int r = 0; r < 4; ++r)
          base[(q * 4 + r) * 32 + nf * 16 + col] = acc[nf][r];
    }
    __syncthreads();
    if (!(wave & 1)) {
#pragma unroll
      for (int nf = 0; nf < 2; ++nf)
#pragma unroll
        for (int r = 0; r < 4; ++r)
          acc[nf][r] += base[(q * 4 + r) * 32 + nf * 16 + col];
      if (z == 0) gemm_epi<2, false, true, false, false>(acc, b1, aq, NN, m0, n0, lane);
      else        gemm_epi<2, false, false, false, false>(acc, nullptr, ak, NN, m0, n0, lane);
    }
  }
  gridbar(cnt, gen, 256);

  // ===== Phase 2: sc[n][m] = b2 + sum_d w2[d] relu(aq[d][n] + ak[d][m]) ====
  {
    float (*aqs)[32] = (float(*)[32])smem;            // 16 KB
    float (*aks)[32] = (float(*)[32])(smem + 16384);  // 16 KB
    float* w2s = (float*)(smem + 32768);              // 1 KB
    const int n0 = (bid >> 4) * 32;
    const int m0 = (bid & 15) * 32;
    const int tn = tid & 31;
    const int tm4 = (tid >> 5) * 4;

    w2s[tid] = w2[tid];

    float s0 = 0.f, s1 = 0.f, s2 = 0.f, s3 = 0.f;
    for (int d0 = 0; d0 < DD; d0 += 128) {
      __syncthreads();
#pragma unroll
      for (int k = 0; k < 16; ++k) {
        const int idx = k * 256 + tid;
        const int r = idx >> 5, cc = idx & 31;
        aqs[r][cc] = aq[(d0 + r) * NN + n0 + cc];
        aks[r][cc] = ak[(d0 + r) * NN + m0 + cc];
      }
      __syncthreads();
      for (int dd = 0; dd < 128; ++dd) {
        const float w = w2s[d0 + dd];
        const float a = aqs[dd][tn];
        const float4 akv = *(const float4*)&aks[dd][tm4];
        s0 += w * fmaxf(a + akv.x, 0.f);
        s1 += w * fmaxf(a + akv.y, 0.f);
        s2 += w * fmaxf(a + akv.z, 0.f);
        s3 += w * fmaxf(a + akv.w, 0.f);
      }
    }
    const float bv = b2[0];
    float4 o; o.x = s0 + bv; o.y = s1 + bv; o.z = s2 + bv; o.w = s3 + bv;
    *(float4*)&sc[(n0 + tn) * NN + m0 + tm4] = o;
  }
  gridbar(cnt, gen, 256);

  // ===== Phase 3: msgT[n][d] = softmax(sc)[n][:] @ src[d][:] (bf16 out) ====
  {
    unsigned short (*Ap)[520] = (unsigned short(*)[520])smem;  // 16.6 KB
    float* red  = (float*)(smem + 16640);                      // 6 KB (NF=2)
    float (*smax)[16] = (float(*)[16])(smem + 22784);
    float (*ssum)[16] = (float(*)[16])(smem + 23808);
    float (*rst)[2]   = (float(*)[2])(smem + 24832);
    const int n0 = (bid >> 3) * 16;   // token rows
    const int d0 = (bid & 7) * 32;    // d tile

    const int r = tid >> 4;
    const int c = tid & 15;
    float4 v[8];
    const float* rp = sc + (n0 + r) * NN + c * 4;
#pragma unroll
    for (int i = 0; i < 8; ++i) v[i] = *(const float4*)(rp + i * 64);

    float mx = -3.0e38f;
#pragma unroll
    for (int i = 0; i < 8; ++i)
      mx = fmaxf(mx, fmaxf(fmaxf(v[i].x, v[i].y), fmaxf(v[i].z, v[i].w)));
    smax[r][c] = mx;
    __syncthreads();
    if (c == 0) {
      float m2 = smax[r][0];
#pragma unroll
      for (int i = 1; i < 16; ++i) m2 = fmaxf(m2, smax[r][i]);
      rst[r][0] = m2;
    }
    __syncthreads();
    mx = rst[r][0];

    float sum = 0.f;
#pragma unroll
    for (int i = 0; i < 8; ++i) {
      v[i].x = __expf(v[i].x - mx); v[i].y = __expf(v[i].y - mx);
      v[i].z = __expf(v[i].z - mx); v[i].w = __expf(v[i].w - mx);
      sum += v[i].x + v[i].y + v[i].z + v[i].w;
    }
    ssum[r][c] = sum;
    __syncthreads();
    if (c == 0) {
      float s2 = ssum[r][0];
#pragma unroll
      for (int i = 1; i < 16; ++i) s2 += ssum[r][i];
      rst[r][1] = s2;
    }
    __syncthreads();
    const float inv = 1.0f / rst[r][1];
#pragma unroll
    for (int i = 0; i < 8; ++i) {
      *(unsigned*)&Ap[r][c * 4 + i * 64]     = pack2(v[i].x * inv, v[i].y * inv);
      *(unsigned*)&Ap[r][c * 4 + i * 64 + 2] = pack2(v[i].z * inv, v[i].w * inv);
    }
    __syncthreads();

    floatx4 acc[2]; acc_zero<2>(acc);
    const int k0w = wave * 128;
    const int arow = lane & 15;
    const int koff = (lane >> 4) << 3;
#pragma unroll
    for (int k = 0; k < 128; k += 32) {
      short8 a = *(const short8*)&Ap[arow][k0w + k + koff];
#pragma unroll
      for (int nf = 0; nf < 2; ++nf) {
        short8 b = ldfrag(srcb, d0 + nf * 16, NN, k0w + k, lane);
        acc[nf] = __builtin_amdgcn_mfma_f32_16x16x32_bf16(a, b, acc[nf], 0, 0, 0);
      }
    }
    ksplit_combine<2>(acc, red, wave, lane);
    if (wave == 0)
      gemm_epi<2, false, false, false, true>(acc, nullptr, msgTb, DD, n0, d0, lane);
  }
  gridbar(cnt, gen, 256);

  // ===== Phase 4: h2T[n][o] = relu([xT|msgT] @ wa^T + ba[o]) (bf16 out) ====
  {
    float* red = (float*)smem;  // 12 KB (NF=4)
    const int m0 = (bid >> 3) * 16;   // token
    const int n0 = (bid & 7) * 64;    // o
    floatx4 acc[4]; acc_zero<4>(acc);
    const unsigned short* A = (wave < 2) ? xT : msgTb;
    gemm_acc<4, 128>(acc, A, DD, (wave & 1) * 128, wab, NN, wave * 128, m0, n0, lane);
    ksplit_combine<4>(acc, red, wave, lane);
    if (wave == 0)
      gemm_epi<4, true, false, true, true>(acc, ba, h2Tb, NN, m0, n0, lane);
  }
  gridbar(cnt, gen, 256);

  // ===== Phase 5: y[o][n] = wb @ h2 + bb[o] (f32 out) ======================
  {
    float* red = (float*)smem;  // 6 KB (NF=2)
    const int m0 = (bid >> 4) * 16;   // o
    const int n0 = (bid & 15) * 32;   // token
    floatx4 acc[2]; acc_zero<2>(acc);
    gemm_acc<2, 128>(acc, wbb, NN, wave * 128, h2Tb, NN, wave * 128, m0, n0, lane);
    ksplit_combine<2>(acc, red, wave, lane);
    if (wave == 0)
      gemm_epi<2, false, true, false, false>(acc, bb, y, NN, m0, n0, lane);
  }
}

// ---------------------------------------------------------------------------
extern "C" void kernel_launch(void* const* d_in, const int* in_sizes, int n_in,
                              void* d_out, int out_size, void* d_ws, size_t ws_size,
                              hipStream_t stream) {
  (void)in_sizes; (void)n_in; (void)out_size; (void)ws_size;

  const float* x   = (const float*)d_in[0];
  const float* src = (const float*)d_in[1];
  const float* w1  = (const float*)d_in[2];
  const float* b1  = (const float*)d_in[3];
  const float* w2  = (const float*)d_in[4];
  const float* b2  = (const float*)d_in[5];
  const float* wa  = (const float*)d_in[6];
  const float* ba  = (const float*)d_in[7];
  const float* wb  = (const float*)d_in[8];
  const float* bb  = (const float*)d_in[9];

  float* y_out  = (float*)d_out;            // (256,512)
  float* sc_out = (float*)d_out + 131072;   // (512,512)

  char* ws = (char*)d_ws;
  unsigned short* w1b   = (unsigned short*)(ws);                 // 256KB
  unsigned short* wab   = (unsigned short*)(ws + (256 << 10));   // 512KB
  unsigned short* wbb   = (unsigned short*)(ws + (768 << 10));   // 256KB
  unsigned short* srcb  = (unsigned short*)(ws + (1024 << 10));  // 256KB
  unsigned short* xT    = (unsigned short*)(ws + (1280 << 10));  // 256KB
  unsigned short* srcT  = (unsigned short*)(ws + (1536 << 10));  // 256KB
  unsigned short* msgTb = (unsigned short*)(ws + (1792 << 10));  // 256KB
  unsigned short* h2Tb  = (unsigned short*)(ws + (2048 << 10));  // 512KB
  float*          aq    = (float*)(ws + (2560 << 10));           // 512KB
  float*          ak    = (float*)(ws + (3072 << 10));           // 512KB
  unsigned*       bar   = (unsigned*)(ws + (3584 << 10));        // 32B

  prep_kernel<<<896, 256, 0, stream>>>(x, src, w1, wa, wb,
                                       w1b, wab, wbb, srcb, xT, srcT, bar);
  mega_kernel<<<256, 256, 0, stream>>>(w1b, xT, srcT, srcb, wab, wbb,
                                       b1, w2, b2, ba, bb,
                                       aq, ak, msgTb, h2Tb, sc_out, y_out, bar);
}

// Round 7
// 122.714 us; speedup vs baseline: 1.7027x; 1.7027x over previous
//
#include <hip/hip_runtime.h>
#include <hip/hip_bf16.h>

#define DD 256
#define NN 512

typedef __attribute__((ext_vector_type(8))) short short8;
typedef __attribute__((ext_vector_type(4))) float floatx4;

// ---- f32 -> bf16 round-to-nearest-even ----
__device__ __forceinline__ unsigned short f2bf(float f) {
  unsigned u = __float_as_uint(f);
  u += 0x7FFFu + ((u >> 16) & 1u);
  return (unsigned short)(u >> 16);
}
__device__ __forceinline__ unsigned pack2(float a, float b) {
  return (unsigned)f2bf(a) | ((unsigned)f2bf(b) << 16);
}
// bf16 (low/high half of dword) -> f32
__device__ __forceinline__ float bflo(unsigned u) { return __uint_as_float(u << 16); }
__device__ __forceinline__ float bfhi(unsigned u) { return __uint_as_float(u & 0xFFFF0000u); }

// ---- MFMA fragment loader (global bf16 rows, k contiguous) ----
__device__ __forceinline__ short8 ldfrag(const unsigned short* __restrict__ base,
                                         int row, int ld, int k, int lane) {
  return *(const short8*)(base + (row + (lane & 15)) * ld + k + ((lane >> 4) << 3));
}

template <int NF>
__device__ __forceinline__ void acc_zero(floatx4 acc[NF]) {
#pragma unroll
  for (int i = 0; i < NF; ++i) {
    acc[i][0] = 0.f; acc[i][1] = 0.f; acc[i][2] = 0.f; acc[i][3] = 0.f;
  }
}

// Split-K combine across 4 waves via LDS; wave 0 ends with the full sum.
template <int NF>
__device__ __forceinline__ void ksplit_combine(floatx4 acc[NF], float* red,
                                               int wave, int lane) {
  const int W = 16 * NF;
  const int col = lane & 15;
  const int q = lane >> 4;
  if (wave > 0) {
    float* base = red + (wave - 1) * 16 * W;
#pragma unroll
    for (int nf = 0; nf < NF; ++nf)
#pragma unroll
      for (int r = 0; r < 4; ++r)
        base[(q * 4 + r) * W + nf * 16 + col] = acc[nf][r];
  }
  __syncthreads();
  if (wave == 0) {
#pragma unroll
    for (int nf = 0; nf < NF; ++nf)
#pragma unroll
      for (int r = 0; r < 4; ++r) {
        const int idx = (q * 4 + r) * W + nf * 16 + col;
        acc[nf][r] += red[idx] + red[16 * W + idx] + red[32 * W + idx];
      }
  }
}

// Epilogue for C-layout (col = lane&15, row = (lane>>4)*4 + r).
template <int NF, bool COLBIAS, bool ROWBIAS, bool RELU, bool OUTBF>
__device__ __forceinline__ void gemm_epi(floatx4 acc[NF],
    const float* __restrict__ bias, void* __restrict__ C, int ldc,
    int m0, int n0, int lane) {
  const int col = lane & 15;
  const int q = lane >> 4;
#pragma unroll
  for (int nf = 0; nf < NF; ++nf) {
    const int n = n0 + nf * 16 + col;
    const float cb = COLBIAS ? bias[n] : 0.0f;
#pragma unroll
    for (int r = 0; r < 4; ++r) {
      const int m = m0 + q * 4 + r;
      float v = acc[nf][r] + cb + (ROWBIAS ? bias[m] : 0.0f);
      if (RELU) v = fmaxf(v, 0.0f);
      if (OUTBF) ((unsigned short*)C)[m * ldc + n] = f2bf(v);
      else       ((float*)C)[m * ldc + n] = v;
    }
  }
}

// ---------------------------------------------------------------------------
// prep: blocks 0..639   flat cvt (w1 128 | wa 256 | wb 128 | src 128)
//       blocks 640..895 transpose+cvt x,src -> xT,srcT [n][d]
//       blocks 896..1023 init y[o][n] = bb[o]  (h2y atomically accumulates)
// ---------------------------------------------------------------------------
__global__ __launch_bounds__(256) void prep_kernel(
    const float* __restrict__ x, const float* __restrict__ src,
    const float* __restrict__ w1, const float* __restrict__ wa,
    const float* __restrict__ wb, const float* __restrict__ bb,
    unsigned short* __restrict__ w1b, unsigned short* __restrict__ wab,
    unsigned short* __restrict__ wbb, unsigned short* __restrict__ srcb,
    unsigned short* __restrict__ xT, unsigned short* __restrict__ srcT,
    float* __restrict__ y) {
  const int bid = blockIdx.x;
  const int tid = threadIdx.x;
  if (bid < 640) {
    const float* in; unsigned short* out; int off;
    if (bid < 128)      { in = w1;  out = w1b; off = bid; }
    else if (bid < 384) { in = wa;  out = wab; off = bid - 128; }
    else if (bid < 512) { in = wb;  out = wbb; off = bid - 384; }
    else                { in = src; out = srcb; off = bid - 512; }
    const int i = off * 1024 + tid * 4;
    const float4 v = *(const float4*)(in + i);
    *(uint2*)(out + i) = make_uint2(pack2(v.x, v.y), pack2(v.z, v.w));
  } else if (bid < 896) {
    __shared__ float tile[32][33];
    const int b = bid - 640;
    const float* in = (b >> 7) ? src : x;
    unsigned short* out = (b >> 7) ? srcT : xT;
    const int t = b & 127;
    const int n0 = (t >> 3) * 32;
    const int d0 = (t & 7) * 32;
    const int tx = tid & 31, ty = tid >> 5;
#pragma unroll
    for (int i = ty; i < 32; i += 8)
      tile[i][tx] = in[(d0 + i) * NN + n0 + tx];
    __syncthreads();
#pragma unroll
    for (int i = ty; i < 32; i += 8)
      out[(n0 + i) * DD + d0 + tx] = f2bf(tile[tx][i]);
  } else {
    const int i = (bid - 896) * 1024 + tid * 4;   // covers 256*512 = 131072
    const float bv = bb[i >> 9];                  // whole float4 shares one o
    float4 o; o.x = bv; o.y = bv; o.z = bv; o.w = bv;
    *(float4*)(y + i) = o;
  }
}

// ---------------------------------------------------------------------------
// QKS: fused aq/ak tile recompute (MFMA -> LDS bf16) + scores.
// grid (16 n-tiles, 16 m-tiles), 256 threads.
// sc[n][m] = b2 + sum_d w2[d] * relu(aq[d][n] + ak[d][m])
// ---------------------------------------------------------------------------
__global__ __launch_bounds__(256) void qks_kernel(
    const unsigned short* __restrict__ w1b, const unsigned short* __restrict__ xT,
    const unsigned short* __restrict__ srcT, const float* __restrict__ b1,
    const float* __restrict__ w2, const float* __restrict__ b2,
    float* __restrict__ sc) {
  // aqs/aks: bf16 [256 d][32 tok], row pad -> 36 shorts (72 B, 8B-aligned rows)
  __shared__ __align__(16) unsigned short aqs[256][36];
  __shared__ __align__(16) unsigned short aks[256][36];
  __shared__ __align__(16) float part[4][32][32];   // 16 KB d-split partials
  __shared__ float w2s[DD];

  const int tid = threadIdx.x;
  const int lane = tid & 63;
  const int wave = tid >> 6;
  const int n0 = blockIdx.x * 32;
  const int m0 = blockIdx.y * 32;

  w2s[tid] = w2[tid];

  // ---- phase A: recompute aq/ak tiles via MFMA, write bf16 to LDS --------
  // 32 jobs: z (0=aq,1=ak) x 16 d-tiles; 8 jobs per wave.
  {
    const int col = lane & 15, q = lane >> 4;
#pragma unroll
    for (int j = 0; j < 8; ++j) {
      const int jid = wave * 8 + j;
      const int z = jid >> 4;
      const int d0t = (jid & 15) * 16;
      const unsigned short* BT = z ? srcT : xT;
      const int tok0 = z ? m0 : n0;
      floatx4 acc[2]; acc_zero<2>(acc);
#pragma unroll
      for (int kc = 0; kc < 8; ++kc) {
        const int c0 = kc * 32;
        short8 a = ldfrag(w1b, d0t, NN, z * 256 + c0, lane);
#pragma unroll
        for (int nf = 0; nf < 2; ++nf) {
          short8 b = ldfrag(BT, tok0 + nf * 16, DD, c0, lane);
          acc[nf] = __builtin_amdgcn_mfma_f32_16x16x32_bf16(a, b, acc[nf], 0, 0, 0);
        }
      }
      // C-layout: row = d (q*4+r), col = token (nf*16+col); +b1[d] for aq
#pragma unroll
      for (int nf = 0; nf < 2; ++nf)
#pragma unroll
        for (int r = 0; r < 4; ++r) {
          const int d = d0t + q * 4 + r;
          float v = acc[nf][r] + (z ? 0.0f : b1[d]);
          (z ? aks : aqs)[d][nf * 16 + col] = f2bf(v);
        }
    }
  }
  __syncthreads();

  // ---- phase B: scores, d split across 4 waves, 4n x 4m per lane ---------
  {
    const int nq = lane & 7;    // n-group of 4
    const int mq = lane >> 3;   // m-group of 4
    float s[4][4];
#pragma unroll
    for (int i = 0; i < 4; ++i)
#pragma unroll
      for (int j = 0; j < 4; ++j) s[i][j] = 0.f;

    const int dbeg = wave * 64;
    for (int dd = dbeg; dd < dbeg + 64; ++dd) {
      const uint2 aw = *(const uint2*)&aqs[dd][nq * 4];
      const uint2 kw = *(const uint2*)&aks[dd][mq * 4];
      const float w = w2s[dd];
      float a[4] = {bflo(aw.x), bfhi(aw.x), bflo(aw.y), bfhi(aw.y)};
      float k[4] = {bflo(kw.x), bfhi(kw.x), bflo(kw.y), bfhi(kw.y)};
#pragma unroll
      for (int i = 0; i < 4; ++i)
#pragma unroll
        for (int j = 0; j < 4; ++j)
          s[i][j] += w * fmaxf(a[i] + k[j], 0.f);
    }
#pragma unroll
    for (int i = 0; i < 4; ++i)
#pragma unroll
      for (int j = 0; j < 4; ++j)
        part[wave][nq * 4 + i][mq * 4 + j] = s[i][j];
  }
  __syncthreads();

  // ---- combine partials + b2, write sc ------------------------------------
  {
    const int n = tid >> 3;          // 0..31
    const int mg = (tid & 7) * 4;    // m float4 group
    float4 p0 = *(const float4*)&part[0][n][mg];
    float4 p1 = *(const float4*)&part[1][n][mg];
    float4 p2 = *(const float4*)&part[2][n][mg];
    float4 p3 = *(const float4*)&part[3][n][mg];
    const float bv = b2[0];
    float4 o;
    o.x = p0.x + p1.x + p2.x + p3.x + bv;
    o.y = p0.y + p1.y + p2.y + p3.y + bv;
    o.z = p0.z + p1.z + p2.z + p3.z + bv;
    o.w = p0.w + p1.w + p2.w + p3.w + bv;
    *(float4*)&sc[(n0 + n) * NN + m0 + mg] = o;
  }
}

// ---------------------------------------------------------------------------
// msgT: softmax (rows n0..n0+15 of sc) fused with P @ src^T (bf16 out).
// grid (8 d-tiles of 32, 32 n-tiles) = 256 blocks; split-K/4 over m.
// ---------------------------------------------------------------------------
__global__ __launch_bounds__(256) void msgT_kernel(
    const float* __restrict__ sc, const unsigned short* __restrict__ srcb,
    unsigned short* __restrict__ msgTb) {
  __shared__ unsigned short Ap[16][520];   // [row][m], +8 pad
  __shared__ float red[1536];
  __shared__ float smax[16][16];
  __shared__ float ssum[16][16];
  __shared__ float rst[16][2];

  const int tid = threadIdx.x;
  const int lane = tid & 63;
  const int wave = tid >> 6;
  const int n0 = blockIdx.y * 16;   // token rows
  const int d0 = blockIdx.x * 32;   // d tile

  const int r = tid >> 4;
  const int c = tid & 15;
  float4 v[8];
  const float* rp = sc + (n0 + r) * NN + c * 4;
#pragma unroll
  for (int i = 0; i < 8; ++i) v[i] = *(const float4*)(rp + i * 64);

  float mx = -3.0e38f;
#pragma unroll
  for (int i = 0; i < 8; ++i)
    mx = fmaxf(mx, fmaxf(fmaxf(v[i].x, v[i].y), fmaxf(v[i].z, v[i].w)));
  smax[r][c] = mx;
  __syncthreads();
  if (c == 0) {
    float m2 = smax[r][0];
#pragma unroll
    for (int i = 1; i < 16; ++i) m2 = fmaxf(m2, smax[r][i]);
    rst[r][0] = m2;
  }
  __syncthreads();
  mx = rst[r][0];

  float sum = 0.f;
#pragma unroll
  for (int i = 0; i < 8; ++i) {
    v[i].x = __expf(v[i].x - mx); v[i].y = __expf(v[i].y - mx);
    v[i].z = __expf(v[i].z - mx); v[i].w = __expf(v[i].w - mx);
    sum += v[i].x + v[i].y + v[i].z + v[i].w;
  }
  ssum[r][c] = sum;
  __syncthreads();
  if (c == 0) {
    float s2 = ssum[r][0];
#pragma unroll
    for (int i = 1; i < 16; ++i) s2 += ssum[r][i];
    rst[r][1] = s2;
  }
  __syncthreads();
  const float inv = 1.0f / rst[r][1];
#pragma unroll
  for (int i = 0; i < 8; ++i) {
    *(unsigned*)&Ap[r][c * 4 + i * 64]     = pack2(v[i].x * inv, v[i].y * inv);
    *(unsigned*)&Ap[r][c * 4 + i * 64 + 2] = pack2(v[i].z * inv, v[i].w * inv);
  }
  __syncthreads();

  floatx4 acc[2]; acc_zero<2>(acc);
  const int k0w = wave * 128;
  const int arow = lane & 15;
  const int koff = (lane >> 4) << 3;
#pragma unroll
  for (int k = 0; k < 128; k += 32) {
    short8 a = *(const short8*)&Ap[arow][k0w + k + koff];
#pragma unroll
    for (int nf = 0; nf < 2; ++nf) {
      short8 b = ldfrag(srcb, d0 + nf * 16, NN, k0w + k, lane);
      acc[nf] = __builtin_amdgcn_mfma_f32_16x16x32_bf16(a, b, acc[nf], 0, 0, 0);
    }
  }
  ksplit_combine<2>(acc, red, wave, lane);
  if (wave == 0)
    gemm_epi<2, false, false, false, true>(acc, nullptr, msgTb, DD, n0, d0, lane);
}

// ---------------------------------------------------------------------------
// h2y: fused h2 = relu([x|msg]@wa^T + ba) (LDS) and y += wb@h2^T (atomic).
// grid 128: (n-tile 16) x (o-quarter 128). y pre-initialized to bb by prep.
// ---------------------------------------------------------------------------
__global__ __launch_bounds__(256) void h2y_kernel(
    const unsigned short* __restrict__ xT, const unsigned short* __restrict__ msgTb,
    const unsigned short* __restrict__ wab, const unsigned short* __restrict__ wbb,
    const float* __restrict__ ba, float* __restrict__ y) {
  __shared__ __align__(16) unsigned short h2L[16][144];  // 288 B rows, 16B-aligned

  const int tid = threadIdx.x;
  const int lane = tid & 63;
  const int wave = tid >> 6;
  const int nt = blockIdx.x >> 2;
  const int qh = blockIdx.x & 3;
  const int n0g = nt * 16;
  const int o0 = qh * 128;

  // ---- phase 1: h2L[n][o_local], o_local in [0,128); wave owns 32 o ------
  {
    floatx4 acc[2]; acc_zero<2>(acc);
    const int ow = o0 + wave * 32;
#pragma unroll
    for (int kc = 0; kc < 16; ++kc) {
      const int c0 = kc * 32;
      short8 a = (c0 < 256) ? ldfrag(xT, n0g, DD, c0, lane)
                            : ldfrag(msgTb, n0g, DD, c0 - 256, lane);
#pragma unroll
      for (int nf = 0; nf < 2; ++nf) {
        short8 b = ldfrag(wab, ow + nf * 16, NN, c0, lane);
        acc[nf] = __builtin_amdgcn_mfma_f32_16x16x32_bf16(a, b, acc[nf], 0, 0, 0);
      }
    }
    const int col = lane & 15, q = lane >> 4;
#pragma unroll
    for (int nf = 0; nf < 2; ++nf) {
      const int ol = wave * 32 + nf * 16 + col;
      const float cb = ba[o0 + ol];
#pragma unroll
      for (int r = 0; r < 4; ++r)
        h2L[q * 4 + r][ol] = f2bf(fmaxf(acc[nf][r] + cb, 0.f));
    }
  }
  __syncthreads();

  // ---- phase 2: y[o2][n] += wb[o2][o0:o0+128] @ h2L^T --------------------
  {
    const int brow = lane & 15;
    const int koff = (lane >> 4) << 3;
    const int col = lane & 15, q = lane >> 4;
#pragma unroll
    for (int t = 0; t < 4; ++t) {
      const int o2t = wave * 64 + t * 16;
      floatx4 acc;
      acc[0] = 0.f; acc[1] = 0.f; acc[2] = 0.f; acc[3] = 0.f;
#pragma unroll
      for (int kc = 0; kc < 4; ++kc) {
        short8 a = ldfrag(wbb, o2t, NN, o0 + kc * 32, lane);
        short8 b = *(const short8*)&h2L[brow][kc * 32 + koff];
        acc = __builtin_amdgcn_mfma_f32_16x16x32_bf16(a, b, acc, 0, 0, 0);
      }
#pragma unroll
      for (int r = 0; r < 4; ++r)
        atomicAdd(&y[(o2t + q * 4 + r) * NN + n0g + col], acc[r]);
    }
  }
}

// ---------------------------------------------------------------------------
extern "C" void kernel_launch(void* const* d_in, const int* in_sizes, int n_in,
                              void* d_out, int out_size, void* d_ws, size_t ws_size,
                              hipStream_t stream) {
  (void)in_sizes; (void)n_in; (void)out_size; (void)ws_size;

  const float* x   = (const float*)d_in[0];
  const float* src = (const float*)d_in[1];
  const float* w1  = (const float*)d_in[2];
  const float* b1  = (const float*)d_in[3];
  const float* w2  = (const float*)d_in[4];
  const float* b2  = (const float*)d_in[5];
  const float* wa  = (const float*)d_in[6];
  const float* ba  = (const float*)d_in[7];
  const float* wb  = (const float*)d_in[8];
  const float* bb  = (const float*)d_in[9];

  float* y_out  = (float*)d_out;            // (256,512)
  float* sc_out = (float*)d_out + 131072;   // (512,512)

  char* ws = (char*)d_ws;
  unsigned short* w1b   = (unsigned short*)(ws);                 // 256KB
  unsigned short* wab   = (unsigned short*)(ws + (256 << 10));   // 512KB
  unsigned short* wbb   = (unsigned short*)(ws + (768 << 10));   // 256KB
  unsigned short* srcb  = (unsigned short*)(ws + (1024 << 10));  // 256KB
  unsigned short* xT    = (unsigned short*)(ws + (1280 << 10));  // 256KB
  unsigned short* srcT  = (unsigned short*)(ws + (1536 << 10));  // 256KB
  unsigned short* msgTb = (unsigned short*)(ws + (1792 << 10));  // 256KB

  prep_kernel<<<1024, 256, 0, stream>>>(x, src, w1, wa, wb, bb,
                                        w1b, wab, wbb, srcb, xT, srcT, y_out);
  qks_kernel<<<dim3(16, 16), 256, 0, stream>>>(w1b, xT, srcT, b1, w2, b2, sc_out);
  msgT_kernel<<<dim3(8, 32), 256, 0, stream>>>(sc_out, srcb, msgTb);
  h2y_kernel<<<128, 256, 0, stream>>>(xT, msgTb, wab, wbb, ba, y_out);
}

// Round 8
// 108.034 us; speedup vs baseline: 1.9340x; 1.1359x over previous
//
#include <hip/hip_runtime.h>
#include <hip/hip_bf16.h>

#define DD 256
#define NN 512

typedef __attribute__((ext_vector_type(8))) short short8;
typedef __attribute__((ext_vector_type(4))) float floatx4;

// ---- f32 -> bf16 round-to-nearest-even ----
__device__ __forceinline__ unsigned short f2bf(float f) {
  unsigned u = __float_as_uint(f);
  u += 0x7FFFu + ((u >> 16) & 1u);
  return (unsigned short)(u >> 16);
}
__device__ __forceinline__ unsigned pack2(float a, float b) {
  return (unsigned)f2bf(a) | ((unsigned)f2bf(b) << 16);
}

// ---- MFMA fragment from global bf16 rows (k contiguous): one 16B load ----
__device__ __forceinline__ short8 ldfrag(const unsigned short* __restrict__ base,
                                         int row, int ld, int k, int lane) {
  return *(const short8*)(base + (row + (lane & 15)) * ld + k + ((lane >> 4) << 3));
}

// ---- MFMA fragment from global f32 rows (k contiguous): 2 float4 + pack ----
__device__ __forceinline__ short8 ldfrag_f32(const float* __restrict__ base,
                                             int row, int ld, int k, int lane) {
  const float* p = base + (row + (lane & 15)) * ld + k + ((lane >> 4) << 3);
  const float4 v0 = *(const float4*)p;
  const float4 v1 = *(const float4*)(p + 4);
  short8 r;
  r[0] = (short)f2bf(v0.x); r[1] = (short)f2bf(v0.y);
  r[2] = (short)f2bf(v0.z); r[3] = (short)f2bf(v0.w);
  r[4] = (short)f2bf(v1.x); r[5] = (short)f2bf(v1.y);
  r[6] = (short)f2bf(v1.z); r[7] = (short)f2bf(v1.w);
  return r;
}

// ---- MFMA fragment from f32 LDS tile stored [k][n] (transposed read) ------
// lane m-row = nrow + (lane&15); k += (lane>>4)*8; 8 scalar reads + pack.
__device__ __forceinline__ short8 ldfragT_lds(const float* __restrict__ xs, int ldxs,
                                              int nrow, int k, int lane) {
  const int n = nrow + (lane & 15);
  const int kk = k + ((lane >> 4) << 3);
  short8 r;
#pragma unroll
  for (int j = 0; j < 8; ++j) r[j] = (short)f2bf(xs[(kk + j) * ldxs + n]);
  return r;
}

template <int NF>
__device__ __forceinline__ void acc_zero(floatx4 acc[NF]) {
#pragma unroll
  for (int i = 0; i < NF; ++i) {
    acc[i][0] = 0.f; acc[i][1] = 0.f; acc[i][2] = 0.f; acc[i][3] = 0.f;
  }
}

// Split-K combine across 4 waves via LDS; wave 0 ends with the full sum.
template <int NF>
__device__ __forceinline__ void ksplit_combine(floatx4 acc[NF], float* red,
                                               int wave, int lane) {
  const int W = 16 * NF;
  const int col = lane & 15;
  const int q = lane >> 4;
  if (wave > 0) {
    float* base = red + (wave - 1) * 16 * W;
#pragma unroll
    for (int nf = 0; nf < NF; ++nf)
#pragma unroll
      for (int r = 0; r < 4; ++r)
        base[(q * 4 + r) * W + nf * 16 + col] = acc[nf][r];
  }
  __syncthreads();
  if (wave == 0) {
#pragma unroll
    for (int nf = 0; nf < NF; ++nf)
#pragma unroll
      for (int r = 0; r < 4; ++r) {
        const int idx = (q * 4 + r) * W + nf * 16 + col;
        acc[nf][r] += red[idx] + red[16 * W + idx] + red[32 * W + idx];
      }
  }
}

// Epilogue for C-layout (col = lane&15, row = (lane>>4)*4 + r).
template <int NF, bool COLBIAS, bool ROWBIAS, bool RELU, bool OUTBF>
__device__ __forceinline__ void gemm_epi(floatx4 acc[NF],
    const float* __restrict__ bias, void* __restrict__ C, int ldc,
    int m0, int n0, int lane) {
  const int col = lane & 15;
  const int q = lane >> 4;
#pragma unroll
  for (int nf = 0; nf < NF; ++nf) {
    const int n = n0 + nf * 16 + col;
    const float cb = COLBIAS ? bias[n] : 0.0f;
#pragma unroll
    for (int r = 0; r < 4; ++r) {
      const int m = m0 + q * 4 + r;
      float v = acc[nf][r] + cb + (ROWBIAS ? bias[m] : 0.0f);
      if (RELU) v = fmaxf(v, 0.0f);
      if (OUTBF) ((unsigned short*)C)[m * ldc + n] = f2bf(v);
      else       ((float*)C)[m * ldc + n] = v;
    }
  }
}

// ---------------------------------------------------------------------------
// aqak: aq[d][n] = w1[:, :256] @ x + b1 ; ak[d][n] = w1[:, 256:] @ src (f32).
// grid (16 n-tiles of 32, 16 d-tiles of 16, 3); z==2 -> y[o][:] = bb[o].
// A = w1 f32 rows (on-the-fly cvt); B = x/src staged f32 in LDS, transposed
// scalar reads. 4 waves split K=256 four ways.
// ---------------------------------------------------------------------------
__global__ __launch_bounds__(256) void aqak_kernel(
    const float* __restrict__ x, const float* __restrict__ src,
    const float* __restrict__ w1, const float* __restrict__ b1,
    const float* __restrict__ bb,
    float* __restrict__ aq, float* __restrict__ ak, float* __restrict__ y) {
  __shared__ float xs[256][33];   // 33.8 KB f32 [k][n]
  __shared__ float red[1536];     // 6 KB split-K partials

  const int tid = threadIdx.x;
  const int z = blockIdx.z;

  if (z == 2) {  // y init: block (x,y) -> o row, 512 floats
    const int o = blockIdx.y * 16 + blockIdx.x;
    const float bv = bb[o];
    float2 v; v.x = bv; v.y = bv;
    *(float2*)&y[o * NN + tid * 2] = v;
    return;
  }

  const int lane = tid & 63;
  const int wave = tid >> 6;
  const int m0 = blockIdx.y * 16;   // d
  const int n0 = blockIdx.x * 32;   // token
  const float* in = z ? src : x;

  // ---- stage x/src tile [256 k][32 n] as f32 (coalesced reads) ----
#pragma unroll
  for (int p = 0; p < 8; ++p) {
    const int d = p * 32 + (tid >> 3);
    const int c4 = (tid & 7) * 4;
    const float4 v = *(const float4*)&in[d * NN + n0 + c4];
    xs[d][c4 + 0] = v.x; xs[d][c4 + 1] = v.y;
    xs[d][c4 + 2] = v.z; xs[d][c4 + 3] = v.w;
  }
  __syncthreads();

  // ---- MFMA: wave w covers k in [w*64, w*64+64) ----
  floatx4 acc[2]; acc_zero<2>(acc);
#pragma unroll
  for (int kc = 0; kc < 2; ++kc) {
    const int kl = wave * 64 + kc * 32;
    short8 a = ldfrag_f32(w1, m0, NN, z * 256 + kl, lane);
#pragma unroll
    for (int nf = 0; nf < 2; ++nf) {
      short8 b = ldfragT_lds(&xs[0][0], 33, nf * 16, kl, lane);
      acc[nf] = __builtin_amdgcn_mfma_f32_16x16x32_bf16(a, b, acc[nf], 0, 0, 0);
    }
  }
  ksplit_combine<2>(acc, red, wave, lane);
  if (wave == 0) {
    if (z == 0) gemm_epi<2, false, true, false, false>(acc, b1, aq, NN, m0, n0, lane);
    else        gemm_epi<2, false, false, false, false>(acc, nullptr, ak, NN, m0, n0, lane);
  }
}

// ---------------------------------------------------------------------------
// scores (R1-proven): sc[n][m] = b2 + sum_d w2[d] relu(aq[d][n] + ak[d][m])
// grid (16,16), 256 threads, direct write.
// ---------------------------------------------------------------------------
__global__ __launch_bounds__(256) void scores_kernel(
    const float* __restrict__ aq, const float* __restrict__ ak,
    const float* __restrict__ w2, const float* __restrict__ b2,
    float* __restrict__ sc) {
  __shared__ float aqs[128][32];
  __shared__ float aks[128][32];
  __shared__ float w2s[DD];

  const int tid = threadIdx.x;
  const int n0 = blockIdx.x * 32;
  const int m0 = blockIdx.y * 32;
  const int tn = tid & 31;
  const int tm4 = (tid >> 5) * 4;

  w2s[tid] = w2[tid];

  float s0 = 0.f, s1 = 0.f, s2 = 0.f, s3 = 0.f;
  for (int d0 = 0; d0 < DD; d0 += 128) {
    __syncthreads();
#pragma unroll
    for (int k = 0; k < 16; ++k) {
      const int idx = k * 256 + tid;
      const int r = idx >> 5, cc = idx & 31;
      aqs[r][cc] = aq[(d0 + r) * NN + n0 + cc];
      aks[r][cc] = ak[(d0 + r) * NN + m0 + cc];
    }
    __syncthreads();
    for (int dd = 0; dd < 128; ++dd) {
      const float w = w2s[d0 + dd];
      const float a = aqs[dd][tn];
      const float4 akv = *(const float4*)&aks[dd][tm4];
      s0 += w * fmaxf(a + akv.x, 0.f);
      s1 += w * fmaxf(a + akv.y, 0.f);
      s2 += w * fmaxf(a + akv.z, 0.f);
      s3 += w * fmaxf(a + akv.w, 0.f);
    }
  }
  const float bv = b2[0];
  float4 o; o.x = s0 + bv; o.y = s1 + bv; o.z = s2 + bv; o.w = s3 + bv;
  *(float4*)&sc[(n0 + tn) * NN + m0 + tm4] = o;
}

// ---------------------------------------------------------------------------
// msgT: softmax(sc rows) fused with P @ src^T (bf16 out); src read f32.
// grid (8 d-tiles of 32, 32 n-tiles) = 256 blocks; split-K/4 over m.
// ---------------------------------------------------------------------------
__global__ __launch_bounds__(256) void msgT_kernel(
    const float* __restrict__ sc, const float* __restrict__ srcf,
    unsigned short* __restrict__ msgTb) {
  __shared__ unsigned short Ap[16][520];
  __shared__ float red[1536];
  __shared__ float smax[16][16];
  __shared__ float ssum[16][16];
  __shared__ float rst[16][2];

  const int tid = threadIdx.x;
  const int lane = tid & 63;
  const int wave = tid >> 6;
  const int n0 = blockIdx.y * 16;
  const int d0 = blockIdx.x * 32;

  const int r = tid >> 4;
  const int c = tid & 15;
  float4 v[8];
  const float* rp = sc + (n0 + r) * NN + c * 4;
#pragma unroll
  for (int i = 0; i < 8; ++i) v[i] = *(const float4*)(rp + i * 64);

  float mx = -3.0e38f;
#pragma unroll
  for (int i = 0; i < 8; ++i)
    mx = fmaxf(mx, fmaxf(fmaxf(v[i].x, v[i].y), fmaxf(v[i].z, v[i].w)));
  smax[r][c] = mx;
  __syncthreads();
  if (c == 0) {
    float m2 = smax[r][0];
#pragma unroll
    for (int i = 1; i < 16; ++i) m2 = fmaxf(m2, smax[r][i]);
    rst[r][0] = m2;
  }
  __syncthreads();
  mx = rst[r][0];

  float sum = 0.f;
#pragma unroll
  for (int i = 0; i < 8; ++i) {
    v[i].x = __expf(v[i].x - mx); v[i].y = __expf(v[i].y - mx);
    v[i].z = __expf(v[i].z - mx); v[i].w = __expf(v[i].w - mx);
    sum += v[i].x + v[i].y + v[i].z + v[i].w;
  }
  ssum[r][c] = sum;
  __syncthreads();
  if (c == 0) {
    float s2 = ssum[r][0];
#pragma unroll
    for (int i = 1; i < 16; ++i) s2 += ssum[r][i];
    rst[r][1] = s2;
  }
  __syncthreads();
  const float inv = 1.0f / rst[r][1];
#pragma unroll
  for (int i = 0; i < 8; ++i) {
    *(unsigned*)&Ap[r][c * 4 + i * 64]     = pack2(v[i].x * inv, v[i].y * inv);
    *(unsigned*)&Ap[r][c * 4 + i * 64 + 2] = pack2(v[i].z * inv, v[i].w * inv);
  }
  __syncthreads();

  floatx4 acc[2]; acc_zero<2>(acc);
  const int k0w = wave * 128;
  const int arow = lane & 15;
  const int koff = (lane >> 4) << 3;
#pragma unroll
  for (int k = 0; k < 128; k += 32) {
    short8 a = *(const short8*)&Ap[arow][k0w + k + koff];
#pragma unroll
    for (int nf = 0; nf < 2; ++nf) {
      short8 b = ldfrag_f32(srcf, d0 + nf * 16, NN, k0w + k, lane);
      acc[nf] = __builtin_amdgcn_mfma_f32_16x16x32_bf16(a, b, acc[nf], 0, 0, 0);
    }
  }
  ksplit_combine<2>(acc, red, wave, lane);
  if (wave == 0)
    gemm_epi<2, false, false, false, true>(acc, nullptr, msgTb, DD, n0, d0, lane);
}

// ---------------------------------------------------------------------------
// h2y: h2 tile = relu([x|msg] @ wa^T + ba) in LDS (bf16), then
//      y[o2][n] += wb[o2][o-slice] @ h2^T via f32 atomicAdd (y pre-set to bb).
// grid 128: (n-tile 16 of 32) x (o-quarter of 4). wa/wb read f32 on the fly.
// ---------------------------------------------------------------------------
__global__ __launch_bounds__(256) void h2y_kernel(
    const float* __restrict__ x, const unsigned short* __restrict__ msgTb,
    const float* __restrict__ waf, const float* __restrict__ wbf,
    const float* __restrict__ ba, float* __restrict__ y) {
  __shared__ float xs[256][17];                           // 17.4 KB f32 [c][n]
  __shared__ __align__(16) unsigned short h2L[16][152];   // 4.9 KB, 2-way reads

  const int tid = threadIdx.x;
  const int lane = tid & 63;
  const int wave = tid >> 6;
  const int nt = blockIdx.x >> 2;
  const int qh = blockIdx.x & 3;
  const int n0g = nt * 16;
  const int o0 = qh * 128;

  // ---- stage x cols n0g..n0g+16 (f32, [c][n]) ----
#pragma unroll
  for (int p = 0; p < 16; ++p) {
    const int d = p * 16 + (tid >> 4);
    const int n = tid & 15;
    xs[d][n] = x[d * NN + n0g + n];
  }
  __syncthreads();

  // ---- phase 1: h2L[n][o_local], wave owns 32 o ----
  {
    floatx4 acc[2]; acc_zero<2>(acc);
    const int ow = o0 + wave * 32;
#pragma unroll
    for (int kc = 0; kc < 16; ++kc) {
      const int c0 = kc * 32;
      short8 a = (c0 < 256) ? ldfragT_lds(&xs[0][0], 17, 0, c0, lane)
                            : ldfrag(msgTb, n0g, DD, c0 - 256, lane);
#pragma unroll
      for (int nf = 0; nf < 2; ++nf) {
        short8 b = ldfrag_f32(waf, ow + nf * 16, NN, c0, lane);
        acc[nf] = __builtin_amdgcn_mfma_f32_16x16x32_bf16(a, b, acc[nf], 0, 0, 0);
      }
    }
    const int col = lane & 15, q = lane >> 4;
#pragma unroll
    for (int nf = 0; nf < 2; ++nf) {
      const int ol = wave * 32 + nf * 16 + col;
      const float cb = ba[o0 + ol];
#pragma unroll
      for (int r = 0; r < 4; ++r)
        h2L[q * 4 + r][ol] = f2bf(fmaxf(acc[nf][r] + cb, 0.f));
    }
  }
  __syncthreads();

  // ---- phase 2: y[o2][n] += wb[o2][o0:o0+128] @ h2L^T ----
  {
    const int brow = lane & 15;
    const int koff = (lane >> 4) << 3;
    const int col = lane & 15, q = lane >> 4;
#pragma unroll
    for (int t = 0; t < 4; ++t) {
      const int o2t = wave * 64 + t * 16;
      floatx4 acc;
      acc[0] = 0.f; acc[1] = 0.f; acc[2] = 0.f; acc[3] = 0.f;
#pragma unroll
      for (int kc = 0; kc < 4; ++kc) {
        short8 a = ldfrag_f32(wbf, o2t, NN, o0 + kc * 32, lane);
        short8 b = *(const short8*)&h2L[brow][kc * 32 + koff];
        acc = __builtin_amdgcn_mfma_f32_16x16x32_bf16(a, b, acc, 0, 0, 0);
      }
#pragma unroll
      for (int r = 0; r < 4; ++r)
        atomicAdd(&y[(o2t + q * 4 + r) * NN + n0g + col], acc[r]);
    }
  }
}

// ---------------------------------------------------------------------------
extern "C" void kernel_launch(void* const* d_in, const int* in_sizes, int n_in,
                              void* d_out, int out_size, void* d_ws, size_t ws_size,
                              hipStream_t stream) {
  (void)in_sizes; (void)n_in; (void)out_size; (void)ws_size;

  const float* x   = (const float*)d_in[0];
  const float* src = (const float*)d_in[1];
  const float* w1  = (const float*)d_in[2];
  const float* b1  = (const float*)d_in[3];
  const float* w2  = (const float*)d_in[4];
  const float* b2  = (const float*)d_in[5];
  const float* wa  = (const float*)d_in[6];
  const float* ba  = (const float*)d_in[7];
  const float* wb  = (const float*)d_in[8];
  const float* bb  = (const float*)d_in[9];

  float* y_out  = (float*)d_out;            // (256,512)
  float* sc_out = (float*)d_out + 131072;   // (512,512)

  char* ws = (char*)d_ws;
  float*          aq    = (float*)(ws);                    // 512KB
  float*          ak    = (float*)(ws + (512 << 10));      // 512KB
  unsigned short* msgTb = (unsigned short*)(ws + (1024 << 10));  // 256KB

  aqak_kernel<<<dim3(16, 16, 3), 256, 0, stream>>>(x, src, w1, b1, bb, aq, ak, y_out);
  scores_kernel<<<dim3(16, 16), 256, 0, stream>>>(aq, ak, w2, b2, sc_out);
  msgT_kernel<<<dim3(8, 32), 256, 0, stream>>>(sc_out, src, msgTb);
  h2y_kernel<<<128, 256, 0, stream>>>(x, msgTb, wa, wb, ba, y_out);
}

// Round 9
// 104.998 us; speedup vs baseline: 1.9900x; 1.0289x over previous
//
#include <hip/hip_runtime.h>
#include <hip/hip_bf16.h>

#define DD 256
#define NN 512

typedef __attribute__((ext_vector_type(8))) short short8;
typedef __attribute__((ext_vector_type(4))) float floatx4;

// ---- f32 -> bf16 round-to-nearest-even ----
__device__ __forceinline__ unsigned short f2bf(float f) {
  unsigned u = __float_as_uint(f);
  u += 0x7FFFu + ((u >> 16) & 1u);
  return (unsigned short)(u >> 16);
}
__device__ __forceinline__ unsigned pack2(float a, float b) {
  return (unsigned)f2bf(a) | ((unsigned)f2bf(b) << 16);
}

// ---- MFMA fragment from global bf16 rows (k contiguous): one 16B load ----
__device__ __forceinline__ short8 ldfrag(const unsigned short* __restrict__ base,
                                         int row, int ld, int k, int lane) {
  return *(const short8*)(base + (row + (lane & 15)) * ld + k + ((lane >> 4) << 3));
}

// ---- MFMA fragment from global f32 rows (k contiguous): 2 float4 + pack ----
__device__ __forceinline__ short8 ldfrag_f32(const float* __restrict__ base,
                                             int row, int ld, int k, int lane) {
  const float* p = base + (row + (lane & 15)) * ld + k + ((lane >> 4) << 3);
  const float4 v0 = *(const float4*)p;
  const float4 v1 = *(const float4*)(p + 4);
  short8 r;
  r[0] = (short)f2bf(v0.x); r[1] = (short)f2bf(v0.y);
  r[2] = (short)f2bf(v0.z); r[3] = (short)f2bf(v0.w);
  r[4] = (short)f2bf(v1.x); r[5] = (short)f2bf(v1.y);
  r[6] = (short)f2bf(v1.z); r[7] = (short)f2bf(v1.w);
  return r;
}

// ---- MFMA fragment, TRANSPOSED, direct from global f32 [k][n] storage -----
// frag rows are n = n0+(lane&15); k = k0+(lane>>4)*8+j. Per j-load the wave
// touches 4 k-rows x 16 consecutive floats = 64B segments (L2-friendly).
__device__ __forceinline__ short8 ldfragT_g(const float* __restrict__ base,
                                            int n0, int ld, int k, int lane) {
  const int n = n0 + (lane & 15);
  const int kk = k + ((lane >> 4) << 3);
  short8 r;
#pragma unroll
  for (int j = 0; j < 8; ++j) r[j] = (short)f2bf(base[(kk + j) * ld + n]);
  return r;
}

template <int NF>
__device__ __forceinline__ void acc_zero(floatx4 acc[NF]) {
#pragma unroll
  for (int i = 0; i < NF; ++i) {
    acc[i][0] = 0.f; acc[i][1] = 0.f; acc[i][2] = 0.f; acc[i][3] = 0.f;
  }
}

// Split-K combine across 4 waves via LDS; wave 0 ends with the full sum.
template <int NF>
__device__ __forceinline__ void ksplit_combine(floatx4 acc[NF], float* red,
                                               int wave, int lane) {
  const int W = 16 * NF;
  const int col = lane & 15;
  const int q = lane >> 4;
  if (wave > 0) {
    float* base = red + (wave - 1) * 16 * W;
#pragma unroll
    for (int nf = 0; nf < NF; ++nf)
#pragma unroll
      for (int r = 0; r < 4; ++r)
        base[(q * 4 + r) * W + nf * 16 + col] = acc[nf][r];
  }
  __syncthreads();
  if (wave == 0) {
#pragma unroll
    for (int nf = 0; nf < NF; ++nf)
#pragma unroll
      for (int r = 0; r < 4; ++r) {
        const int idx = (q * 4 + r) * W + nf * 16 + col;
        acc[nf][r] += red[idx] + red[16 * W + idx] + red[32 * W + idx];
      }
  }
}

// Epilogue for C-layout (col = lane&15, row = (lane>>4)*4 + r).
template <int NF, bool COLBIAS, bool ROWBIAS, bool RELU, bool OUTBF>
__device__ __forceinline__ void gemm_epi(floatx4 acc[NF],
    const float* __restrict__ bias, void* __restrict__ C, int ldc,
    int m0, int n0, int lane) {
  const int col = lane & 15;
  const int q = lane >> 4;
#pragma unroll
  for (int nf = 0; nf < NF; ++nf) {
    const int n = n0 + nf * 16 + col;
    const float cb = COLBIAS ? bias[n] : 0.0f;
#pragma unroll
    for (int r = 0; r < 4; ++r) {
      const int m = m0 + q * 4 + r;
      float v = acc[nf][r] + cb + (ROWBIAS ? bias[m] : 0.0f);
      if (RELU) v = fmaxf(v, 0.0f);
      if (OUTBF) ((unsigned short*)C)[m * ldc + n] = f2bf(v);
      else       ((float*)C)[m * ldc + n] = v;
    }
  }
}

// ---------------------------------------------------------------------------
// aqak: aq[d][n] = w1[:, :256] @ x + b1 ; ak[d][n] = w1[:, 256:] @ src (f32).
// grid (16 n-tiles of 32, 16 d-tiles of 16, 3); z==2 -> y[o][:] = bb[o].
// A = w1 f32 rows (on-the-fly cvt); B = x/src gathered transposed straight
// from global (64B segments). 4 waves split K=256 four ways. No staging LDS.
// ---------------------------------------------------------------------------
__global__ __launch_bounds__(256) void aqak_kernel(
    const float* __restrict__ x, const float* __restrict__ src,
    const float* __restrict__ w1, const float* __restrict__ b1,
    const float* __restrict__ bb,
    float* __restrict__ aq, float* __restrict__ ak, float* __restrict__ y) {
  __shared__ float red[1536];

  const int tid = threadIdx.x;
  const int z = blockIdx.z;

  if (z == 2) {  // y init: block (x,y) -> o row, 512 floats
    const int o = blockIdx.y * 16 + blockIdx.x;
    const float bv = bb[o];
    float2 v; v.x = bv; v.y = bv;
    *(float2*)&y[o * NN + tid * 2] = v;
    return;
  }

  const int lane = tid & 63;
  const int wave = tid >> 6;
  const int m0 = blockIdx.y * 16;   // d
  const int n0 = blockIdx.x * 32;   // token
  const float* in = z ? src : x;

  floatx4 acc[2]; acc_zero<2>(acc);
#pragma unroll
  for (int kc = 0; kc < 2; ++kc) {
    const int kl = wave * 64 + kc * 32;
    short8 a = ldfrag_f32(w1, m0, NN, z * 256 + kl, lane);
#pragma unroll
    for (int nf = 0; nf < 2; ++nf) {
      short8 b = ldfragT_g(in, n0 + nf * 16, NN, kl, lane);
      acc[nf] = __builtin_amdgcn_mfma_f32_16x16x32_bf16(a, b, acc[nf], 0, 0, 0);
    }
  }
  ksplit_combine<2>(acc, red, wave, lane);
  if (wave == 0) {
    if (z == 0) gemm_epi<2, false, true, false, false>(acc, b1, aq, NN, m0, n0, lane);
    else        gemm_epi<2, false, false, false, false>(acc, nullptr, ak, NN, m0, n0, lane);
  }
}

// ---------------------------------------------------------------------------
// scores (R1-proven): sc[n][m] = b2 + sum_d w2[d] relu(aq[d][n] + ak[d][m])
// grid (16,16), 256 threads, direct write.
// ---------------------------------------------------------------------------
__global__ __launch_bounds__(256) void scores_kernel(
    const float* __restrict__ aq, const float* __restrict__ ak,
    const float* __restrict__ w2, const float* __restrict__ b2,
    float* __restrict__ sc) {
  __shared__ float aqs[128][32];
  __shared__ float aks[128][32];
  __shared__ float w2s[DD];

  const int tid = threadIdx.x;
  const int n0 = blockIdx.x * 32;
  const int m0 = blockIdx.y * 32;
  const int tn = tid & 31;
  const int tm4 = (tid >> 5) * 4;

  w2s[tid] = w2[tid];

  float s0 = 0.f, s1 = 0.f, s2 = 0.f, s3 = 0.f;
  for (int d0 = 0; d0 < DD; d0 += 128) {
    __syncthreads();
#pragma unroll
    for (int k = 0; k < 16; ++k) {
      const int idx = k * 256 + tid;
      const int r = idx >> 5, cc = idx & 31;
      aqs[r][cc] = aq[(d0 + r) * NN + n0 + cc];
      aks[r][cc] = ak[(d0 + r) * NN + m0 + cc];
    }
    __syncthreads();
    for (int dd = 0; dd < 128; ++dd) {
      const float w = w2s[d0 + dd];
      const float a = aqs[dd][tn];
      const float4 akv = *(const float4*)&aks[dd][tm4];
      s0 += w * fmaxf(a + akv.x, 0.f);
      s1 += w * fmaxf(a + akv.y, 0.f);
      s2 += w * fmaxf(a + akv.z, 0.f);
      s3 += w * fmaxf(a + akv.w, 0.f);
    }
  }
  const float bv = b2[0];
  float4 o; o.x = s0 + bv; o.y = s1 + bv; o.z = s2 + bv; o.w = s3 + bv;
  *(float4*)&sc[(n0 + tn) * NN + m0 + tm4] = o;
}

// ---------------------------------------------------------------------------
// msgT: softmax(sc rows) fused with P @ src^T (bf16 out); src read f32.
// grid (8 d-tiles of 32, 32 n-tiles) = 256 blocks; split-K/4 over m.
// ---------------------------------------------------------------------------
__global__ __launch_bounds__(256) void msgT_kernel(
    const float* __restrict__ sc, const float* __restrict__ srcf,
    unsigned short* __restrict__ msgTb) {
  __shared__ unsigned short Ap[16][520];
  __shared__ float red[1536];
  __shared__ float smax[16][16];
  __shared__ float ssum[16][16];
  __shared__ float rst[16][2];

  const int tid = threadIdx.x;
  const int lane = tid & 63;
  const int wave = tid >> 6;
  const int n0 = blockIdx.y * 16;
  const int d0 = blockIdx.x * 32;

  const int r = tid >> 4;
  const int c = tid & 15;
  float4 v[8];
  const float* rp = sc + (n0 + r) * NN + c * 4;
#pragma unroll
  for (int i = 0; i < 8; ++i) v[i] = *(const float4*)(rp + i * 64);

  float mx = -3.0e38f;
#pragma unroll
  for (int i = 0; i < 8; ++i)
    mx = fmaxf(mx, fmaxf(fmaxf(v[i].x, v[i].y), fmaxf(v[i].z, v[i].w)));
  smax[r][c] = mx;
  __syncthreads();
  if (c == 0) {
    float m2 = smax[r][0];
#pragma unroll
    for (int i = 1; i < 16; ++i) m2 = fmaxf(m2, smax[r][i]);
    rst[r][0] = m2;
  }
  __syncthreads();
  mx = rst[r][0];

  float sum = 0.f;
#pragma unroll
  for (int i = 0; i < 8; ++i) {
    v[i].x = __expf(v[i].x - mx); v[i].y = __expf(v[i].y - mx);
    v[i].z = __expf(v[i].z - mx); v[i].w = __expf(v[i].w - mx);
    sum += v[i].x + v[i].y + v[i].z + v[i].w;
  }
  ssum[r][c] = sum;
  __syncthreads();
  if (c == 0) {
    float s2 = ssum[r][0];
#pragma unroll
    for (int i = 1; i < 16; ++i) s2 += ssum[r][i];
    rst[r][1] = s2;
  }
  __syncthreads();
  const float inv = 1.0f / rst[r][1];
#pragma unroll
  for (int i = 0; i < 8; ++i) {
    *(unsigned*)&Ap[r][c * 4 + i * 64]     = pack2(v[i].x * inv, v[i].y * inv);
    *(unsigned*)&Ap[r][c * 4 + i * 64 + 2] = pack2(v[i].z * inv, v[i].w * inv);
  }
  __syncthreads();

  floatx4 acc[2]; acc_zero<2>(acc);
  const int k0w = wave * 128;
  const int arow = lane & 15;
  const int koff = (lane >> 4) << 3;
#pragma unroll
  for (int k = 0; k < 128; k += 32) {
    short8 a = *(const short8*)&Ap[arow][k0w + k + koff];
#pragma unroll
    for (int nf = 0; nf < 2; ++nf) {
      short8 b = ldfrag_f32(srcf, d0 + nf * 16, NN, k0w + k, lane);
      acc[nf] = __builtin_amdgcn_mfma_f32_16x16x32_bf16(a, b, acc[nf], 0, 0, 0);
    }
  }
  ksplit_combine<2>(acc, red, wave, lane);
  if (wave == 0)
    gemm_epi<2, false, false, false, true>(acc, nullptr, msgTb, DD, n0, d0, lane);
}

// ---------------------------------------------------------------------------
// h2y: h2 o-slice = relu([x|msg] @ wa^T + ba) in LDS (bf16), then
//      y[o2][n] += wb[o2][o-slice] @ h2^T via f32 atomicAdd (y pre-set to bb).
// grid (8 o-slices of 64, 32 n-tiles of 16) = 256 blocks. x gathered
// transposed direct from global; wa/wb cvt on the fly.
// ---------------------------------------------------------------------------
__global__ __launch_bounds__(256) void h2y_kernel(
    const float* __restrict__ x, const unsigned short* __restrict__ msgTb,
    const float* __restrict__ waf, const float* __restrict__ wbf,
    const float* __restrict__ ba, float* __restrict__ y) {
  __shared__ __align__(16) unsigned short h2L[16][72];  // 64 o + 8 pad

  const int tid = threadIdx.x;
  const int lane = tid & 63;
  const int wave = tid >> 6;
  const int o0 = blockIdx.x * 64;
  const int n0g = blockIdx.y * 16;

  // ---- phase 1: h2L[n][o_local], wave owns 16 o ----
  {
    floatx4 acc;
    acc[0] = 0.f; acc[1] = 0.f; acc[2] = 0.f; acc[3] = 0.f;
    const int ow = o0 + wave * 16;
#pragma unroll
    for (int kc = 0; kc < 16; ++kc) {
      const int c0 = kc * 32;
      short8 a = (c0 < 256) ? ldfragT_g(x, n0g, NN, c0, lane)
                            : ldfrag(msgTb, n0g, DD, c0 - 256, lane);
      short8 b = ldfrag_f32(waf, ow, NN, c0, lane);
      acc = __builtin_amdgcn_mfma_f32_16x16x32_bf16(a, b, acc, 0, 0, 0);
    }
    const int col = lane & 15, q = lane >> 4;
    const float cb = ba[o0 + wave * 16 + col];
#pragma unroll
    for (int r = 0; r < 4; ++r)
      h2L[q * 4 + r][wave * 16 + col] = f2bf(fmaxf(acc[r] + cb, 0.f));
  }
  __syncthreads();

  // ---- phase 2: y[o2][n] += wb[o2][o0:o0+64] @ h2L^T ----
  {
    const int brow = lane & 15;
    const int koff = (lane >> 4) << 3;
    const int col = lane & 15, q = lane >> 4;
#pragma unroll
    for (int t = 0; t < 4; ++t) {
      const int o2t = wave * 64 + t * 16;
      floatx4 acc;
      acc[0] = 0.f; acc[1] = 0.f; acc[2] = 0.f; acc[3] = 0.f;
#pragma unroll
      for (int kc = 0; kc < 2; ++kc) {
        short8 a = ldfrag_f32(wbf, o2t, NN, o0 + kc * 32, lane);
        short8 b = *(const short8*)&h2L[brow][kc * 32 + koff];
        acc = __builtin_amdgcn_mfma_f32_16x16x32_bf16(a, b, acc, 0, 0, 0);
      }
#pragma unroll
      for (int r = 0; r < 4; ++r)
        atomicAdd(&y[(o2t + q * 4 + r) * NN + n0g + col], acc[r]);
    }
  }
}

// ---------------------------------------------------------------------------
extern "C" void kernel_launch(void* const* d_in, const int* in_sizes, int n_in,
                              void* d_out, int out_size, void* d_ws, size_t ws_size,
                              hipStream_t stream) {
  (void)in_sizes; (void)n_in; (void)out_size; (void)ws_size;

  const float* x   = (const float*)d_in[0];
  const float* src = (const float*)d_in[1];
  const float* w1  = (const float*)d_in[2];
  const float* b1  = (const float*)d_in[3];
  const float* w2  = (const float*)d_in[4];
  const float* b2  = (const float*)d_in[5];
  const float* wa  = (const float*)d_in[6];
  const float* ba  = (const float*)d_in[7];
  const float* wb  = (const float*)d_in[8];
  const float* bb  = (const float*)d_in[9];

  float* y_out  = (float*)d_out;            // (256,512)
  float* sc_out = (float*)d_out + 131072;   // (512,512)

  char* ws = (char*)d_ws;
  float*          aq    = (float*)(ws);                          // 512KB
  float*          ak    = (float*)(ws + (512 << 10));            // 512KB
  unsigned short* msgTb = (unsigned short*)(ws + (1024 << 10));  // 256KB

  aqak_kernel<<<dim3(16, 16, 3), 256, 0, stream>>>(x, src, w1, b1, bb, aq, ak, y_out);
  scores_kernel<<<dim3(16, 16), 256, 0, stream>>>(aq, ak, w2, b2, sc_out);
  msgT_kernel<<<dim3(8, 32), 256, 0, stream>>>(sc_out, src, msgTb);
  h2y_kernel<<<dim3(8, 32), 256, 0, stream>>>(x, msgTb, wa, wb, ba, y_out);
}

// Round 10
// 104.660 us; speedup vs baseline: 1.9964x; 1.0032x over previous
//
#include <hip/hip_runtime.h>
#include <hip/hip_bf16.h>

#define DD 256
#define NN 512

typedef __attribute__((ext_vector_type(8))) short short8;
typedef __attribute__((ext_vector_type(4))) float floatx4;

// ---- f32 -> bf16 round-to-nearest-even ----
__device__ __forceinline__ unsigned short f2bf(float f) {
  unsigned u = __float_as_uint(f);
  u += 0x7FFFu + ((u >> 16) & 1u);
  return (unsigned short)(u >> 16);
}
__device__ __forceinline__ unsigned pack2(float a, float b) {
  return (unsigned)f2bf(a) | ((unsigned)f2bf(b) << 16);
}

// ---- MFMA fragment from global bf16 rows (k contiguous): one 16B load ----
__device__ __forceinline__ short8 ldfrag(const unsigned short* __restrict__ base,
                                         int row, int ld, int k, int lane) {
  return *(const short8*)(base + (row + (lane & 15)) * ld + k + ((lane >> 4) << 3));
}

// ---- MFMA fragment from global f32 rows (k contiguous): 2 float4 + pack ----
__device__ __forceinline__ short8 ldfrag_f32(const float* __restrict__ base,
                                             int row, int ld, int k, int lane) {
  const float* p = base + (row + (lane & 15)) * ld + k + ((lane >> 4) << 3);
  const float4 v0 = *(const float4*)p;
  const float4 v1 = *(const float4*)(p + 4);
  short8 r;
  r[0] = (short)f2bf(v0.x); r[1] = (short)f2bf(v0.y);
  r[2] = (short)f2bf(v0.z); r[3] = (short)f2bf(v0.w);
  r[4] = (short)f2bf(v1.x); r[5] = (short)f2bf(v1.y);
  r[6] = (short)f2bf(v1.z); r[7] = (short)f2bf(v1.w);
  return r;
}

// ---- MFMA fragment, TRANSPOSED, direct from global f32 [k][n] storage -----
__device__ __forceinline__ short8 ldfragT_g(const float* __restrict__ base,
                                            int n0, int ld, int k, int lane) {
  const int n = n0 + (lane & 15);
  const int kk = k + ((lane >> 4) << 3);
  short8 r;
#pragma unroll
  for (int j = 0; j < 8; ++j) r[j] = (short)f2bf(base[(kk + j) * ld + n]);
  return r;
}

template <int NF>
__device__ __forceinline__ void acc_zero(floatx4 acc[NF]) {
#pragma unroll
  for (int i = 0; i < NF; ++i) {
    acc[i][0] = 0.f; acc[i][1] = 0.f; acc[i][2] = 0.f; acc[i][3] = 0.f;
  }
}

// Split-K combine across 4 waves via LDS; wave 0 ends with the full sum.
template <int NF>
__device__ __forceinline__ void ksplit_combine(floatx4 acc[NF], float* red,
                                               int wave, int lane) {
  const int W = 16 * NF;
  const int col = lane & 15;
  const int q = lane >> 4;
  if (wave > 0) {
    float* base = red + (wave - 1) * 16 * W;
#pragma unroll
    for (int nf = 0; nf < NF; ++nf)
#pragma unroll
      for (int r = 0; r < 4; ++r)
        base[(q * 4 + r) * W + nf * 16 + col] = acc[nf][r];
  }
  __syncthreads();
  if (wave == 0) {
#pragma unroll
    for (int nf = 0; nf < NF; ++nf)
#pragma unroll
      for (int r = 0; r < 4; ++r) {
        const int idx = (q * 4 + r) * W + nf * 16 + col;
        acc[nf][r] += red[idx] + red[16 * W + idx] + red[32 * W + idx];
      }
  }
}

// Epilogue for C-layout (col = lane&15, row = (lane>>4)*4 + r).
template <int NF, bool COLBIAS, bool ROWBIAS, bool RELU, bool OUTBF>
__device__ __forceinline__ void gemm_epi(floatx4 acc[NF],
    const float* __restrict__ bias, void* __restrict__ C, int ldc,
    int m0, int n0, int lane) {
  const int col = lane & 15;
  const int q = lane >> 4;
#pragma unroll
  for (int nf = 0; nf < NF; ++nf) {
    const int n = n0 + nf * 16 + col;
    const float cb = COLBIAS ? bias[n] : 0.0f;
#pragma unroll
    for (int r = 0; r < 4; ++r) {
      const int m = m0 + q * 4 + r;
      float v = acc[nf][r] + cb + (ROWBIAS ? bias[m] : 0.0f);
      if (RELU) v = fmaxf(v, 0.0f);
      if (OUTBF) ((unsigned short*)C)[m * ldc + n] = f2bf(v);
      else       ((float*)C)[m * ldc + n] = v;
    }
  }
}

// ---------------------------------------------------------------------------
// aqak: aq[d][n] = w1[:, :256] @ x + b1 ; ak[d][n] = w1[:, 256:] @ src (f32).
// grid (16, 16, 3); z==2 blocks: y[o][:] = bb[o] AND emit xT bf16 [n][d]
// (consumed only by h2y, which launches strictly later).
// ---------------------------------------------------------------------------
__global__ __launch_bounds__(256) void aqak_kernel(
    const float* __restrict__ x, const float* __restrict__ src,
    const float* __restrict__ w1, const float* __restrict__ b1,
    const float* __restrict__ bb,
    float* __restrict__ aq, float* __restrict__ ak, float* __restrict__ y,
    unsigned short* __restrict__ xT) {
  __shared__ float red[1536];

  const int tid = threadIdx.x;
  const int z = blockIdx.z;

  if (z == 2) {
    const int c = blockIdx.y * 16 + blockIdx.x;   // 0..255
    // y init: row o = c
    const float bv = bb[c];
    float2 v; v.x = bv; v.y = bv;
    *(float2*)&y[c * NN + tid * 2] = v;
    // xT cvt: tokens c*2, c*2+1 (256 d each)
    const int n0t = c * 2 + (tid >> 7);
    const int d2 = (tid & 127) * 2;
    const float f0 = x[d2 * NN + n0t];
    const float f1 = x[(d2 + 1) * NN + n0t];
    *(unsigned*)&xT[n0t * DD + d2] = pack2(f0, f1);
    return;
  }

  const int lane = tid & 63;
  const int wave = tid >> 6;
  const int m0 = blockIdx.y * 16;   // d
  const int n0 = blockIdx.x * 32;   // token
  const float* in = z ? src : x;

  floatx4 acc[2]; acc_zero<2>(acc);
#pragma unroll
  for (int kc = 0; kc < 2; ++kc) {
    const int kl = wave * 64 + kc * 32;
    short8 a = ldfrag_f32(w1, m0, NN, z * 256 + kl, lane);
#pragma unroll
    for (int nf = 0; nf < 2; ++nf) {
      short8 b = ldfragT_g(in, n0 + nf * 16, NN, kl, lane);
      acc[nf] = __builtin_amdgcn_mfma_f32_16x16x32_bf16(a, b, acc[nf], 0, 0, 0);
    }
  }
  ksplit_combine<2>(acc, red, wave, lane);
  if (wave == 0) {
    if (z == 0) gemm_epi<2, false, true, false, false>(acc, b1, aq, NN, m0, n0, lane);
    else        gemm_epi<2, false, false, false, false>(acc, nullptr, ak, NN, m0, n0, lane);
  }
}

// ---------------------------------------------------------------------------
// scores v2: sc[n][m] = b2 + sum_d w2[d] relu(aq[d][n] + ak[d][m])
// grid (16,16). d split across 4 waves; lane does 4n x 4m outer-product
// from f32 LDS (8-lane broadcast per float4); LDS partial combine.
// ---------------------------------------------------------------------------
__global__ __launch_bounds__(256) void scores_kernel(
    const float* __restrict__ aq, const float* __restrict__ ak,
    const float* __restrict__ w2, const float* __restrict__ b2,
    float* __restrict__ sc) {
  __shared__ __align__(16) float aqs[256][36];   // [d][n], 144B rows
  __shared__ __align__(16) float aks[256][36];
  __shared__ __align__(16) float part[4][32][32];
  __shared__ float w2s[DD];

  const int tid = threadIdx.x;
  const int lane = tid & 63;
  const int wave = tid >> 6;
  const int n0 = blockIdx.x * 32;
  const int m0 = blockIdx.y * 32;

  w2s[tid] = w2[tid];

  // ---- stage aq/ak tiles (f32, coalesced 128B groups) ----
#pragma unroll
  for (int i = 0; i < 8; ++i) {
    const int idx = i * 256 + tid;
    const int row = idx >> 3;
    const int c4 = (idx & 7) * 4;
    *(float4*)&aqs[row][c4] = *(const float4*)&aq[row * NN + n0 + c4];
    *(float4*)&aks[row][c4] = *(const float4*)&ak[row * NN + m0 + c4];
  }
  __syncthreads();

  // ---- outer-product phase: wave covers 64 d; lane = (nq 0..7, mq 0..7) ----
  {
    const int nq = lane & 7;
    const int mq = lane >> 3;
    float s[4][4];
#pragma unroll
    for (int i = 0; i < 4; ++i)
#pragma unroll
      for (int j = 0; j < 4; ++j) s[i][j] = 0.f;

    const int dbeg = wave * 64;
    for (int dd = dbeg; dd < dbeg + 64; ++dd) {
      const float4 a4 = *(const float4*)&aqs[dd][nq * 4];
      const float4 k4 = *(const float4*)&aks[dd][mq * 4];
      const float w = w2s[dd];
      const float a[4] = {a4.x, a4.y, a4.z, a4.w};
      const float k[4] = {k4.x, k4.y, k4.z, k4.w};
#pragma unroll
      for (int i = 0; i < 4; ++i)
#pragma unroll
        for (int j = 0; j < 4; ++j)
          s[i][j] += w * fmaxf(a[i] + k[j], 0.f);
    }
#pragma unroll
    for (int i = 0; i < 4; ++i) {
      float4 o; o.x = s[i][0]; o.y = s[i][1]; o.z = s[i][2]; o.w = s[i][3];
      *(float4*)&part[wave][nq * 4 + i][mq * 4] = o;
    }
  }
  __syncthreads();

  // ---- combine 4 wave-partials + b2, write sc ----
  {
    const int n = tid >> 3;
    const int mg = (tid & 7) * 4;
    const float4 p0 = *(const float4*)&part[0][n][mg];
    const float4 p1 = *(const float4*)&part[1][n][mg];
    const float4 p2 = *(const float4*)&part[2][n][mg];
    const float4 p3 = *(const float4*)&part[3][n][mg];
    const float bv = b2[0];
    float4 o;
    o.x = p0.x + p1.x + p2.x + p3.x + bv;
    o.y = p0.y + p1.y + p2.y + p3.y + bv;
    o.z = p0.z + p1.z + p2.z + p3.z + bv;
    o.w = p0.w + p1.w + p2.w + p3.w + bv;
    *(float4*)&sc[(n0 + n) * NN + m0 + mg] = o;
  }
}

// ---------------------------------------------------------------------------
// msgT: softmax(sc rows) fused with P @ src^T (bf16 out); src read f32.
// grid (8 d-tiles of 32, 32 n-tiles) = 256 blocks; split-K/4 over m.
// ---------------------------------------------------------------------------
__global__ __launch_bounds__(256) void msgT_kernel(
    const float* __restrict__ sc, const float* __restrict__ srcf,
    unsigned short* __restrict__ msgTb) {
  __shared__ unsigned short Ap[16][520];
  __shared__ float red[1536];
  __shared__ float smax[16][16];
  __shared__ float ssum[16][16];
  __shared__ float rst[16][2];

  const int tid = threadIdx.x;
  const int lane = tid & 63;
  const int wave = tid >> 6;
  const int n0 = blockIdx.y * 16;
  const int d0 = blockIdx.x * 32;

  const int r = tid >> 4;
  const int c = tid & 15;
  float4 v[8];
  const float* rp = sc + (n0 + r) * NN + c * 4;
#pragma unroll
  for (int i = 0; i < 8; ++i) v[i] = *(const float4*)(rp + i * 64);

  float mx = -3.0e38f;
#pragma unroll
  for (int i = 0; i < 8; ++i)
    mx = fmaxf(mx, fmaxf(fmaxf(v[i].x, v[i].y), fmaxf(v[i].z, v[i].w)));
  smax[r][c] = mx;
  __syncthreads();
  if (c == 0) {
    float m2 = smax[r][0];
#pragma unroll
    for (int i = 1; i < 16; ++i) m2 = fmaxf(m2, smax[r][i]);
    rst[r][0] = m2;
  }
  __syncthreads();
  mx = rst[r][0];

  float sum = 0.f;
#pragma unroll
  for (int i = 0; i < 8; ++i) {
    v[i].x = __expf(v[i].x - mx); v[i].y = __expf(v[i].y - mx);
    v[i].z = __expf(v[i].z - mx); v[i].w = __expf(v[i].w - mx);
    sum += v[i].x + v[i].y + v[i].z + v[i].w;
  }
  ssum[r][c] = sum;
  __syncthreads();
  if (c == 0) {
    float s2 = ssum[r][0];
#pragma unroll
    for (int i = 1; i < 16; ++i) s2 += ssum[r][i];
    rst[r][1] = s2;
  }
  __syncthreads();
  const float inv = 1.0f / rst[r][1];
#pragma unroll
  for (int i = 0; i < 8; ++i) {
    *(unsigned*)&Ap[r][c * 4 + i * 64]     = pack2(v[i].x * inv, v[i].y * inv);
    *(unsigned*)&Ap[r][c * 4 + i * 64 + 2] = pack2(v[i].z * inv, v[i].w * inv);
  }
  __syncthreads();

  floatx4 acc[2]; acc_zero<2>(acc);
  const int k0w = wave * 128;
  const int arow = lane & 15;
  const int koff = (lane >> 4) << 3;
#pragma unroll
  for (int k = 0; k < 128; k += 32) {
    short8 a = *(const short8*)&Ap[arow][k0w + k + koff];
#pragma unroll
    for (int nf = 0; nf < 2; ++nf) {
      short8 b = ldfrag_f32(srcf, d0 + nf * 16, NN, k0w + k, lane);
      acc[nf] = __builtin_amdgcn_mfma_f32_16x16x32_bf16(a, b, acc[nf], 0, 0, 0);
    }
  }
  ksplit_combine<2>(acc, red, wave, lane);
  if (wave == 0)
    gemm_epi<2, false, false, false, true>(acc, nullptr, msgTb, DD, n0, d0, lane);
}

// ---------------------------------------------------------------------------
// h2y: h2 o-slice = relu([x|msg] @ wa^T + ba) in LDS (bf16), then
//      y[o2][n] += wb[o2][o-slice] @ h2^T via f32 atomicAdd (y pre-set to bb).
// grid (8 o-slices of 64, 32 n-tiles of 16). x read via precomputed xT bf16.
// ---------------------------------------------------------------------------
__global__ __launch_bounds__(256) void h2y_kernel(
    const unsigned short* __restrict__ xT, const unsigned short* __restrict__ msgTb,
    const float* __restrict__ waf, const float* __restrict__ wbf,
    const float* __restrict__ ba, float* __restrict__ y) {
  __shared__ __align__(16) unsigned short h2L[16][72];  // 64 o + 8 pad

  const int tid = threadIdx.x;
  const int lane = tid & 63;
  const int wave = tid >> 6;
  const int o0 = blockIdx.x * 64;
  const int n0g = blockIdx.y * 16;

  // ---- phase 1: h2L[n][o_local], wave owns 16 o ----
  {
    floatx4 acc;
    acc[0] = 0.f; acc[1] = 0.f; acc[2] = 0.f; acc[3] = 0.f;
    const int ow = o0 + wave * 16;
#pragma unroll
    for (int kc = 0; kc < 16; ++kc) {
      const int c0 = kc * 32;
      short8 a = (c0 < 256) ? ldfrag(xT, n0g, DD, c0, lane)
                            : ldfrag(msgTb, n0g, DD, c0 - 256, lane);
      short8 b = ldfrag_f32(waf, ow, NN, c0, lane);
      acc = __builtin_amdgcn_mfma_f32_16x16x32_bf16(a, b, acc, 0, 0, 0);
    }
    const int col = lane & 15, q = lane >> 4;
    const float cb = ba[o0 + wave * 16 + col];
#pragma unroll
    for (int r = 0; r < 4; ++r)
      h2L[q * 4 + r][wave * 16 + col] = f2bf(fmaxf(acc[r] + cb, 0.f));
  }
  __syncthreads();

  // ---- phase 2: y[o2][n] += wb[o2][o0:o0+64] @ h2L^T ----
  {
    const int brow = lane & 15;
    const int koff = (lane >> 4) << 3;
    const int col = lane & 15, q = lane >> 4;
#pragma unroll
    for (int t = 0; t < 4; ++t) {
      const int o2t = wave * 64 + t * 16;
      floatx4 acc;
      acc[0] = 0.f; acc[1] = 0.f; acc[2] = 0.f; acc[3] = 0.f;
#pragma unroll
      for (int kc = 0; kc < 2; ++kc) {
        short8 a = ldfrag_f32(wbf, o2t, NN, o0 + kc * 32, lane);
        short8 b = *(const short8*)&h2L[brow][kc * 32 + koff];
        acc = __builtin_amdgcn_mfma_f32_16x16x32_bf16(a, b, acc, 0, 0, 0);
      }
#pragma unroll
      for (int r = 0; r < 4; ++r)
        atomicAdd(&y[(o2t + q * 4 + r) * NN + n0g + col], acc[r]);
    }
  }
}

// ---------------------------------------------------------------------------
extern "C" void kernel_launch(void* const* d_in, const int* in_sizes, int n_in,
                              void* d_out, int out_size, void* d_ws, size_t ws_size,
                              hipStream_t stream) {
  (void)in_sizes; (void)n_in; (void)out_size; (void)ws_size;

  const float* x   = (const float*)d_in[0];
  const float* src = (const float*)d_in[1];
  const float* w1  = (const float*)d_in[2];
  const float* b1  = (const float*)d_in[3];
  const float* w2  = (const float*)d_in[4];
  const float* b2  = (const float*)d_in[5];
  const float* wa  = (const float*)d_in[6];
  const float* ba  = (const float*)d_in[7];
  const float* wb  = (const float*)d_in[8];
  const float* bb  = (const float*)d_in[9];

  float* y_out  = (float*)d_out;            // (256,512)
  float* sc_out = (float*)d_out + 131072;   // (512,512)

  char* ws = (char*)d_ws;
  float*          aq    = (float*)(ws);                          // 512KB
  float*          ak    = (float*)(ws + (512 << 10));            // 512KB
  unsigned short* msgTb = (unsigned short*)(ws + (1024 << 10));  // 256KB
  unsigned short* xT    = (unsigned short*)(ws + (1280 << 10));  // 256KB

  aqak_kernel<<<dim3(16, 16, 3), 256, 0, stream>>>(x, src, w1, b1, bb, aq, ak,
                                                   y_out, xT);
  scores_kernel<<<dim3(16, 16), 256, 0, stream>>>(aq, ak, w2, b2, sc_out);
  msgT_kernel<<<dim3(8, 32), 256, 0, stream>>>(sc_out, src, msgTb);
  h2y_kernel<<<dim3(8, 32), 256, 0, stream>>>(xT, msgTb, wa, wb, ba, y_out);
}